// Round 6
// baseline (136.388 us; speedup 1.0000x reference)
//
#include <hip/hip_runtime.h>
#include <math.h>

// TopK router: logits = x @ W^T + bias; top-2; softmax over the 2; scatter.
// x: [N=16384, H=4096] fp32, W: [E=64, H=4096] fp32, bias: [64] fp32.
// d_out: [N*64] final (fp32) then [N*2] selected_experts written as floats.
//
// Round 6: same verified MFMA structure as round 5 (3-term bf16 split,
// 6 products hh+hm+mh+mm+hl+lh, err ~2^-25), but W's split is HOISTED into
// a pre-kernel that writes h/m/l bf16 planes (3 x 512 KB, L2-resident) into
// d_ws. Round 5 re-split W per block (134M of 201M total splits) -> the
// main loop was split-VALU-bound (576 cyc VALU vs 240 cyc MFMA per chunk).
// Now only X is split in-loop; split math identical -> logits bit-identical.

constexpr int E_EXPERTS = 64;
constexpr int H_DIM = 4096;
constexpr int BLOCK = 256;           // 4 waves
constexpr int ROWS_B = 32;           // rows per block
constexpr int KSPLIT = 4;            // one K-quarter per wave
constexpr int KQ = H_DIM / KSPLIT;   // 1024
constexpr int KC = 32;               // k per chunk = one MFMA k-step
constexpr int NCH = KQ / KC;         // 32
constexpr int W_ELEMS = E_EXPERTS * H_DIM;  // 262144

typedef __attribute__((ext_vector_type(8))) short short8;
typedef __attribute__((ext_vector_type(4))) float f32x4;

__device__ __forceinline__ float4 ld4(const float* p) {
  return *reinterpret_cast<const float4*>(p);
}
__device__ __forceinline__ short8 lds8(const unsigned short* p) {
  return *reinterpret_cast<const short8*>(p);
}

__device__ __forceinline__ unsigned short bf_rne(float x) {
  unsigned u = __builtin_bit_cast(unsigned, x);
  return (unsigned short)((u + 0x7fffu + ((u >> 16) & 1u)) >> 16);
}
__device__ __forceinline__ float bf2f(unsigned short b) {
  return __builtin_bit_cast(float, ((unsigned)b) << 16);
}
// x = h + m + l + err, |err| <= 2^-25 |x|. (h,m trunc; l RNE; residuals exact)
__device__ __forceinline__ void split3(float x, unsigned short& h,
                                       unsigned short& m, unsigned short& l) {
  unsigned short hb = (unsigned short)(__builtin_bit_cast(unsigned, x) >> 16);
  float r1 = x - bf2f(hb);
  unsigned short mb = (unsigned short)(__builtin_bit_cast(unsigned, r1) >> 16);
  float r2 = r1 - bf2f(mb);
  h = hb;
  m = mb;
  l = bf_rne(r2);
}
__device__ __forceinline__ void split3_8(float4 a, float4 b, short8& h,
                                         short8& m, short8& l) {
  unsigned short hh, mm, ll;
  split3(a.x, hh, mm, ll); h[0] = (short)hh; m[0] = (short)mm; l[0] = (short)ll;
  split3(a.y, hh, mm, ll); h[1] = (short)hh; m[1] = (short)mm; l[1] = (short)ll;
  split3(a.z, hh, mm, ll); h[2] = (short)hh; m[2] = (short)mm; l[2] = (short)ll;
  split3(a.w, hh, mm, ll); h[3] = (short)hh; m[3] = (short)mm; l[3] = (short)ll;
  split3(b.x, hh, mm, ll); h[4] = (short)hh; m[4] = (short)mm; l[4] = (short)ll;
  split3(b.y, hh, mm, ll); h[5] = (short)hh; m[5] = (short)mm; l[5] = (short)ll;
  split3(b.z, hh, mm, ll); h[6] = (short)hh; m[6] = (short)mm; l[6] = (short)ll;
  split3(b.w, hh, mm, ll); h[7] = (short)hh; m[7] = (short)mm; l[7] = (short)ll;
}

// Pre-kernel: split W into h/m/l bf16 planes (same math as split3).
__global__ __launch_bounds__(256) void split_w_kernel(
    const float* __restrict__ w, unsigned short* __restrict__ wh,
    unsigned short* __restrict__ wm, unsigned short* __restrict__ wl) {
  const int i = (blockIdx.x * 256 + threadIdx.x) * 4;
  float4 v = ld4(w + i);
  ushort4 h4, m4, l4;
  split3(v.x, h4.x, m4.x, l4.x);
  split3(v.y, h4.y, m4.y, l4.y);
  split3(v.z, h4.z, m4.z, l4.z);
  split3(v.w, h4.w, m4.w, l4.w);
  *reinterpret_cast<ushort4*>(wh + i) = h4;
  *reinterpret_cast<ushort4*>(wm + i) = m4;
  *reinterpret_cast<ushort4*>(wl + i) = l4;
}

__global__ __launch_bounds__(BLOCK, 2) void topk_router_mfma(
    const float* __restrict__ x, const unsigned short* __restrict__ wh,
    const unsigned short* __restrict__ wm,
    const unsigned short* __restrict__ wl, const float* __restrict__ bias,
    float* __restrict__ out_final, float* __restrict__ out_idx) {
  __shared__ float part[KSPLIT][ROWS_B][E_EXPERTS + 4];

  const int tid = threadIdx.x;
  const int lane = tid & 63;
  const int kg = tid >> 6;  // K-quarter of this wave
  const int rowBase = blockIdx.x * ROWS_B;
  const int lrow = lane & 15;
  const int lk = (lane >> 4) * 8;

  const float* __restrict__ xp0 =
      x + (size_t)(rowBase + lrow) * H_DIM + kg * KQ + lk;
  const float* __restrict__ xp1 = xp0 + (size_t)16 * H_DIM;
  const size_t woff = (size_t)lrow * H_DIM + kg * KQ + lk;
  const unsigned short* __restrict__ whp = wh + woff;
  const unsigned short* __restrict__ wmp = wm + woff;
  const unsigned short* __restrict__ wlp = wl + woff;

  f32x4 acc00 = {0.f, 0.f, 0.f, 0.f}, acc01 = acc00, acc02 = acc00,
        acc03 = acc00, acc10 = acc00, acc11 = acc00, acc12 = acc00,
        acc13 = acc00;

  float4 xf0a, xf0b, xf1a, xf1b;

#define LOADX(c)                                  \
  do {                                            \
    const size_t o = (size_t)(c)*KC;              \
    xf0a = ld4(xp0 + o); xf0b = ld4(xp0 + o + 4); \
    xf1a = ld4(xp1 + o); xf1b = ld4(xp1 + o + 4); \
  } while (0)

  LOADX(0);
  for (int c = 0; c < NCH; ++c) {
    const size_t o = (size_t)c * KC;
    // Issue W loads (L2-resident) first; X split below covers their latency.
    short8 b0h = lds8(whp + o);
    short8 b1h = lds8(whp + o + (size_t)16 * H_DIM);
    short8 b2h = lds8(whp + o + (size_t)32 * H_DIM);
    short8 b3h = lds8(whp + o + (size_t)48 * H_DIM);
    short8 b0m = lds8(wmp + o);
    short8 b1m = lds8(wmp + o + (size_t)16 * H_DIM);
    short8 b2m = lds8(wmp + o + (size_t)32 * H_DIM);
    short8 b3m = lds8(wmp + o + (size_t)48 * H_DIM);
    short8 b0l = lds8(wlp + o);
    short8 b1l = lds8(wlp + o + (size_t)16 * H_DIM);
    short8 b2l = lds8(wlp + o + (size_t)32 * H_DIM);
    short8 b3l = lds8(wlp + o + (size_t)48 * H_DIM);

    short8 ah0, am0, al0, ah1, am1, al1;
    split3_8(xf0a, xf0b, ah0, am0, al0);
    split3_8(xf1a, xf1b, ah1, am1, al1);
    if (c + 1 < NCH) LOADX(c + 1);  // prefetch next X (HBM)

#define MM(d, a, b) d = __builtin_amdgcn_mfma_f32_16x16x32_bf16(a, b, d, 0, 0, 0)
#define PROD6(d, Ah, Am, Al, Bh, Bm, Bl)                      \
  MM(d, Ah, Bh); MM(d, Ah, Bm); MM(d, Am, Bh); MM(d, Am, Bm); \
  MM(d, Ah, Bl); MM(d, Al, Bh)
    PROD6(acc00, ah0, am0, al0, b0h, b0m, b0l);
    PROD6(acc10, ah1, am1, al1, b0h, b0m, b0l);
    PROD6(acc01, ah0, am0, al0, b1h, b1m, b1l);
    PROD6(acc11, ah1, am1, al1, b1h, b1m, b1l);
    PROD6(acc02, ah0, am0, al0, b2h, b2m, b2l);
    PROD6(acc12, ah1, am1, al1, b2h, b2m, b2l);
    PROD6(acc03, ah0, am0, al0, b3h, b3m, b3l);
    PROD6(acc13, ah1, am1, al1, b3h, b3m, b3l);
  }

  // C/D layout (m89-verified): col = lane&15 (expert), row = (lane>>4)*4+reg.
  const int pr = (lane >> 4) * 4;
  const int pc = lane & 15;
#define STORE_ACC(A, rf, bf)                       \
  part[kg][(rf)*16 + pr + 0][(bf)*16 + pc] = A[0]; \
  part[kg][(rf)*16 + pr + 1][(bf)*16 + pc] = A[1]; \
  part[kg][(rf)*16 + pr + 2][(bf)*16 + pc] = A[2]; \
  part[kg][(rf)*16 + pr + 3][(bf)*16 + pc] = A[3];
  STORE_ACC(acc00, 0, 0)
  STORE_ACC(acc01, 0, 1)
  STORE_ACC(acc02, 0, 2)
  STORE_ACC(acc03, 0, 3)
  STORE_ACC(acc10, 1, 0)
  STORE_ACC(acc11, 1, 1)
  STORE_ACC(acc12, 1, 2)
  STORE_ACC(acc13, 1, 3)
  __syncthreads();

  // Epilogue: 8 threads/row, 8 experts each; ordered 4-way partial sum,
  // stable top-2 scan, shfl_xor merge (d=1,2,4), softmax, scatter.
  const int r = tid >> 3;
  const int eb = (tid & 7) * 8;
  const int n = rowBase + r;

  float v8[8];
#pragma unroll
  for (int j = 0; j < 8; ++j) {
    int e = eb + j;
    v8[j] = ((part[0][r][e] + part[1][r][e]) + (part[2][r][e] + part[3][r][e])) +
            bias[e];
  }

  float av = -INFINITY, bv = -INFINITY;
  int ai = E_EXPERTS, bi = E_EXPERTS;
#pragma unroll
  for (int j = 0; j < 8; ++j) {
    int e = eb + j;
    float v = v8[j];
    bool beats_a = (v > av) || (v == av && e < ai);
    bool beats_b = (v > bv) || (v == bv && e < bi);
    if (beats_a) {
      bv = av; bi = ai; av = v; ai = e;
    } else if (beats_b) {
      bv = v; bi = e;
    }
  }
#pragma unroll
  for (int d = 1; d < 8; d <<= 1) {
    float av2 = __shfl_xor(av, d);
    float bv2 = __shfl_xor(bv, d);
    int ai2 = __shfl_xor(ai, d);
    int bi2 = __shfl_xor(bi, d);
    bool afirst = (av > av2) || (av == av2 && ai < ai2);
    float na, nb;
    int nai, nbi;
    if (afirst) {
      na = av; nai = ai;
      bool t = (bv > av2) || (bv == av2 && bi < ai2);
      nb = t ? bv : av2;
      nbi = t ? bi : ai2;
    } else {
      na = av2; nai = ai2;
      bool t = (av > bv2) || (av == bv2 && ai < bi2);
      nb = t ? av : bv2;
      nbi = t ? ai : bi2;
    }
    av = na; ai = nai; bv = nb; bi = nbi;
  }

  float e1 = expf(bv - av);
  float denom = 1.0f + e1;
  float p0 = 1.0f / denom;
  float p1 = e1 / denom;

#pragma unroll
  for (int i = 0; i < 2; ++i) {
    float4 o4;
    float* po = &o4.x;
#pragma unroll
    for (int j = 0; j < 4; ++j) {
      int e = eb + i * 4 + j;
      po[j] = (e == ai) ? p0 : (e == bi) ? p1 : 0.0f;
    }
    *reinterpret_cast<float4*>(&out_final[(size_t)n * E_EXPERTS + eb + i * 4]) =
        o4;
  }
  if ((tid & 7) == 0) {
    out_idx[(size_t)n * 2 + 0] = (float)ai;
    out_idx[(size_t)n * 2 + 1] = (float)bi;
  }
}

extern "C" void kernel_launch(void* const* d_in, const int* in_sizes, int n_in,
                              void* d_out, int out_size, void* d_ws,
                              size_t ws_size, hipStream_t stream) {
  const float* x = (const float*)d_in[0];
  const float* w = (const float*)d_in[1];
  const float* bias = (const float*)d_in[2];
  const int N = in_sizes[0] / H_DIM;  // 16384
  float* out_final = (float*)d_out;
  float* out_idx = out_final + (size_t)N * E_EXPERTS;

  unsigned short* wh = (unsigned short*)d_ws;  // 3 planes x 512 KB
  unsigned short* wm = wh + W_ELEMS;
  unsigned short* wl = wm + W_ELEMS;

  split_w_kernel<<<W_ELEMS / (256 * 4), 256, 0, stream>>>(w, wh, wm, wl);
  topk_router_mfma<<<N / ROWS_B, BLOCK, 0, stream>>>(x, wh, wm, wl, bias,
                                                     out_final, out_idx);
}

// Round 7
// 134.856 us; speedup vs baseline: 1.0114x; 1.0114x over previous
//
#include <hip/hip_runtime.h>
#include <math.h>

// TopK router: logits = x @ W^T + bias; top-2; softmax over the 2; scatter.
// x: [N=16384, H=4096] fp32, W: [E=64, H=4096] fp32, bias: [64] fp32.
// d_out: [N*64] final (fp32) then [N*2] selected_experts written as floats.
//
// Round 7: round 6 (pre-split W into h/m/l bf16 planes in d_ws; 3-term
// split, 6 MFMA products, err ~2^-25, logits bit-identical to the passing
// round 5) + sched_barrier(0) fences. Round 6's VGPR=72 showed the machine
// scheduler sank each W load to just before its consuming MFMA (liveness
// minimization) -> serial load->wait->MFMA ladders, latency-bound at 11%
// MfmaUtil. Fences pin: [12 W loads] | [X split ~270cyc covers L2 latency;
// X prefetch c+1] | [48 MFMAs]. One amortized waitcnt per chunk.

constexpr int E_EXPERTS = 64;
constexpr int H_DIM = 4096;
constexpr int BLOCK = 256;           // 4 waves
constexpr int ROWS_B = 32;           // rows per block
constexpr int KSPLIT = 4;            // one K-quarter per wave
constexpr int KQ = H_DIM / KSPLIT;   // 1024
constexpr int KC = 32;               // k per chunk = one MFMA k-step
constexpr int NCH = KQ / KC;         // 32
constexpr int W_ELEMS = E_EXPERTS * H_DIM;  // 262144

typedef __attribute__((ext_vector_type(8))) short short8;
typedef __attribute__((ext_vector_type(4))) float f32x4;

__device__ __forceinline__ float4 ld4(const float* p) {
  return *reinterpret_cast<const float4*>(p);
}
__device__ __forceinline__ short8 lds8(const unsigned short* p) {
  return *reinterpret_cast<const short8*>(p);
}

__device__ __forceinline__ unsigned short bf_rne(float x) {
  unsigned u = __builtin_bit_cast(unsigned, x);
  return (unsigned short)((u + 0x7fffu + ((u >> 16) & 1u)) >> 16);
}
__device__ __forceinline__ float bf2f(unsigned short b) {
  return __builtin_bit_cast(float, ((unsigned)b) << 16);
}
// x = h + m + l + err, |err| <= 2^-25 |x|. (h,m trunc; l RNE; residuals exact)
__device__ __forceinline__ void split3(float x, unsigned short& h,
                                       unsigned short& m, unsigned short& l) {
  unsigned short hb = (unsigned short)(__builtin_bit_cast(unsigned, x) >> 16);
  float r1 = x - bf2f(hb);
  unsigned short mb = (unsigned short)(__builtin_bit_cast(unsigned, r1) >> 16);
  float r2 = r1 - bf2f(mb);
  h = hb;
  m = mb;
  l = bf_rne(r2);
}
__device__ __forceinline__ void split3_8(float4 a, float4 b, short8& h,
                                         short8& m, short8& l) {
  unsigned short hh, mm, ll;
  split3(a.x, hh, mm, ll); h[0] = (short)hh; m[0] = (short)mm; l[0] = (short)ll;
  split3(a.y, hh, mm, ll); h[1] = (short)hh; m[1] = (short)mm; l[1] = (short)ll;
  split3(a.z, hh, mm, ll); h[2] = (short)hh; m[2] = (short)mm; l[2] = (short)ll;
  split3(a.w, hh, mm, ll); h[3] = (short)hh; m[3] = (short)mm; l[3] = (short)ll;
  split3(b.x, hh, mm, ll); h[4] = (short)hh; m[4] = (short)mm; l[4] = (short)ll;
  split3(b.y, hh, mm, ll); h[5] = (short)hh; m[5] = (short)mm; l[5] = (short)ll;
  split3(b.z, hh, mm, ll); h[6] = (short)hh; m[6] = (short)mm; l[6] = (short)ll;
  split3(b.w, hh, mm, ll); h[7] = (short)hh; m[7] = (short)mm; l[7] = (short)ll;
}

// Pre-kernel: split W into h/m/l bf16 planes (same math as split3).
__global__ __launch_bounds__(256) void split_w_kernel(
    const float* __restrict__ w, unsigned short* __restrict__ wh,
    unsigned short* __restrict__ wm, unsigned short* __restrict__ wl) {
  const int i = (blockIdx.x * 256 + threadIdx.x) * 4;
  float4 v = ld4(w + i);
  ushort4 h4, m4, l4;
  split3(v.x, h4.x, m4.x, l4.x);
  split3(v.y, h4.y, m4.y, l4.y);
  split3(v.z, h4.z, m4.z, l4.z);
  split3(v.w, h4.w, m4.w, l4.w);
  *reinterpret_cast<ushort4*>(wh + i) = h4;
  *reinterpret_cast<ushort4*>(wm + i) = m4;
  *reinterpret_cast<ushort4*>(wl + i) = l4;
}

__global__ __launch_bounds__(BLOCK, 2) void topk_router_mfma(
    const float* __restrict__ x, const unsigned short* __restrict__ wh,
    const unsigned short* __restrict__ wm,
    const unsigned short* __restrict__ wl, const float* __restrict__ bias,
    float* __restrict__ out_final, float* __restrict__ out_idx) {
  __shared__ float part[KSPLIT][ROWS_B][E_EXPERTS + 4];

  const int tid = threadIdx.x;
  const int lane = tid & 63;
  const int kg = tid >> 6;  // K-quarter of this wave
  const int rowBase = blockIdx.x * ROWS_B;
  const int lrow = lane & 15;
  const int lk = (lane >> 4) * 8;

  const float* __restrict__ xp0 =
      x + (size_t)(rowBase + lrow) * H_DIM + kg * KQ + lk;
  const float* __restrict__ xp1 = xp0 + (size_t)16 * H_DIM;
  const size_t woff = (size_t)lrow * H_DIM + kg * KQ + lk;
  const unsigned short* __restrict__ whp = wh + woff;
  const unsigned short* __restrict__ wmp = wm + woff;
  const unsigned short* __restrict__ wlp = wl + woff;

  f32x4 acc00 = {0.f, 0.f, 0.f, 0.f}, acc01 = acc00, acc02 = acc00,
        acc03 = acc00, acc10 = acc00, acc11 = acc00, acc12 = acc00,
        acc13 = acc00;

  float4 xf0a, xf0b, xf1a, xf1b;

#define LOADX(c)                                  \
  do {                                            \
    const size_t o = (size_t)(c)*KC;              \
    xf0a = ld4(xp0 + o); xf0b = ld4(xp0 + o + 4); \
    xf1a = ld4(xp1 + o); xf1b = ld4(xp1 + o + 4); \
  } while (0)

  LOADX(0);
  for (int c = 0; c < NCH; ++c) {
    const size_t o = (size_t)c * KC;
    // ---- Phase 1: issue all 12 W loads (L2-resident planes). ----
    short8 b0h = lds8(whp + o);
    short8 b1h = lds8(whp + o + (size_t)16 * H_DIM);
    short8 b2h = lds8(whp + o + (size_t)32 * H_DIM);
    short8 b3h = lds8(whp + o + (size_t)48 * H_DIM);
    short8 b0m = lds8(wmp + o);
    short8 b1m = lds8(wmp + o + (size_t)16 * H_DIM);
    short8 b2m = lds8(wmp + o + (size_t)32 * H_DIM);
    short8 b3m = lds8(wmp + o + (size_t)48 * H_DIM);
    short8 b0l = lds8(wlp + o);
    short8 b1l = lds8(wlp + o + (size_t)16 * H_DIM);
    short8 b2l = lds8(wlp + o + (size_t)32 * H_DIM);
    short8 b3l = lds8(wlp + o + (size_t)48 * H_DIM);
    // Fence: loads may not sink past here (round-6 pathology: scheduler
    // sank each load to its consuming MFMA, VGPR=72, serial waits).
    __builtin_amdgcn_sched_barrier(0);

    // ---- Phase 2: X split (~270 cyc VALU, covers W L2 latency) + X
    // prefetch for next chunk (HBM; covered by MFMA block + next split).
    short8 ah0, am0, al0, ah1, am1, al1;
    split3_8(xf0a, xf0b, ah0, am0, al0);
    split3_8(xf1a, xf1b, ah1, am1, al1);
    if (c + 1 < NCH) LOADX(c + 1);
    __builtin_amdgcn_sched_barrier(0);

    // ---- Phase 3: 48 MFMAs. ----
#define MM(d, a, b) d = __builtin_amdgcn_mfma_f32_16x16x32_bf16(a, b, d, 0, 0, 0)
#define PROD6(d, Ah, Am, Al, Bh, Bm, Bl)                      \
  MM(d, Ah, Bh); MM(d, Ah, Bm); MM(d, Am, Bh); MM(d, Am, Bm); \
  MM(d, Ah, Bl); MM(d, Al, Bh)
    PROD6(acc00, ah0, am0, al0, b0h, b0m, b0l);
    PROD6(acc10, ah1, am1, al1, b0h, b0m, b0l);
    PROD6(acc01, ah0, am0, al0, b1h, b1m, b1l);
    PROD6(acc11, ah1, am1, al1, b1h, b1m, b1l);
    PROD6(acc02, ah0, am0, al0, b2h, b2m, b2l);
    PROD6(acc12, ah1, am1, al1, b2h, b2m, b2l);
    PROD6(acc03, ah0, am0, al0, b3h, b3m, b3l);
    PROD6(acc13, ah1, am1, al1, b3h, b3m, b3l);
  }

  // C/D layout (m89-verified): col = lane&15 (expert), row = (lane>>4)*4+reg.
  const int pr = (lane >> 4) * 4;
  const int pc = lane & 15;
#define STORE_ACC(A, rf, bf)                       \
  part[kg][(rf)*16 + pr + 0][(bf)*16 + pc] = A[0]; \
  part[kg][(rf)*16 + pr + 1][(bf)*16 + pc] = A[1]; \
  part[kg][(rf)*16 + pr + 2][(bf)*16 + pc] = A[2]; \
  part[kg][(rf)*16 + pr + 3][(bf)*16 + pc] = A[3];
  STORE_ACC(acc00, 0, 0)
  STORE_ACC(acc01, 0, 1)
  STORE_ACC(acc02, 0, 2)
  STORE_ACC(acc03, 0, 3)
  STORE_ACC(acc10, 1, 0)
  STORE_ACC(acc11, 1, 1)
  STORE_ACC(acc12, 1, 2)
  STORE_ACC(acc13, 1, 3)
  __syncthreads();

  // Epilogue: 8 threads/row, 8 experts each; ordered 4-way partial sum,
  // stable top-2 scan, shfl_xor merge (d=1,2,4), softmax, scatter.
  const int r = tid >> 3;
  const int eb = (tid & 7) * 8;
  const int n = rowBase + r;

  float v8[8];
#pragma unroll
  for (int j = 0; j < 8; ++j) {
    int e = eb + j;
    v8[j] = ((part[0][r][e] + part[1][r][e]) + (part[2][r][e] + part[3][r][e])) +
            bias[e];
  }

  float av = -INFINITY, bv = -INFINITY;
  int ai = E_EXPERTS, bi = E_EXPERTS;
#pragma unroll
  for (int j = 0; j < 8; ++j) {
    int e = eb + j;
    float v = v8[j];
    bool beats_a = (v > av) || (v == av && e < ai);
    bool beats_b = (v > bv) || (v == bv && e < bi);
    if (beats_a) {
      bv = av; bi = ai; av = v; ai = e;
    } else if (beats_b) {
      bv = v; bi = e;
    }
  }
#pragma unroll
  for (int d = 1; d < 8; d <<= 1) {
    float av2 = __shfl_xor(av, d);
    float bv2 = __shfl_xor(bv, d);
    int ai2 = __shfl_xor(ai, d);
    int bi2 = __shfl_xor(bi, d);
    bool afirst = (av > av2) || (av == av2 && ai < ai2);
    float na, nb;
    int nai, nbi;
    if (afirst) {
      na = av; nai = ai;
      bool t = (bv > av2) || (bv == av2 && bi < ai2);
      nb = t ? bv : av2;
      nbi = t ? bi : ai2;
    } else {
      na = av2; nai = ai2;
      bool t = (av > bv2) || (av == bv2 && ai < bi2);
      nb = t ? av : bv2;
      nbi = t ? ai : bi2;
    }
    av = na; ai = nai; bv = nb; bi = nbi;
  }

  float e1 = expf(bv - av);
  float denom = 1.0f + e1;
  float p0 = 1.0f / denom;
  float p1 = e1 / denom;

#pragma unroll
  for (int i = 0; i < 2; ++i) {
    float4 o4;
    float* po = &o4.x;
#pragma unroll
    for (int j = 0; j < 4; ++j) {
      int e = eb + i * 4 + j;
      po[j] = (e == ai) ? p0 : (e == bi) ? p1 : 0.0f;
    }
    *reinterpret_cast<float4*>(&out_final[(size_t)n * E_EXPERTS + eb + i * 4]) =
        o4;
  }
  if ((tid & 7) == 0) {
    out_idx[(size_t)n * 2 + 0] = (float)ai;
    out_idx[(size_t)n * 2 + 1] = (float)bi;
  }
}

extern "C" void kernel_launch(void* const* d_in, const int* in_sizes, int n_in,
                              void* d_out, int out_size, void* d_ws,
                              size_t ws_size, hipStream_t stream) {
  const float* x = (const float*)d_in[0];
  const float* w = (const float*)d_in[1];
  const float* bias = (const float*)d_in[2];
  const int N = in_sizes[0] / H_DIM;  // 16384
  float* out_final = (float*)d_out;
  float* out_idx = out_final + (size_t)N * E_EXPERTS;

  unsigned short* wh = (unsigned short*)d_ws;  // 3 planes x 512 KB
  unsigned short* wm = wh + W_ELEMS;
  unsigned short* wl = wm + W_ELEMS;

  split_w_kernel<<<W_ELEMS / (256 * 4), 256, 0, stream>>>(w, wh, wm, wl);
  topk_router_mfma<<<N / ROWS_B, BLOCK, 0, stream>>>(x, wh, wm, wl, bias,
                                                     out_final, out_idx);
}

// Round 8
// 102.560 us; speedup vs baseline: 1.3298x; 1.3149x over previous
//
#include <hip/hip_runtime.h>
#include <math.h>

// TopK router: logits = x @ W^T + bias; top-2; softmax over the 2; scatter.
// x: [N=16384, H=4096] fp32, W: [E=64, H=4096] fp32, bias: [64] fp32.
// d_out: [N*64] final (fp32) then [N*2] selected_experts written as floats.
//
// Round 8: W pre-split into h/m/l bf16 planes (round 6), but consumed via
// double-buffered LDS staging (m97 pattern) instead of per-lane global
// loads: rounds 6/7 were latency-serialized on L2/L3 W loads (~3200
// cyc/chunk vs ~550 work; sched_barrier didn't fix it, VGPR stayed 84).
// Block = 8 waves = 4 row-groups(16 rows) x 2 K-halves; per 32-k step the
// block stages 24 KB of W tiles (both K-halves, 3 planes, padded rows) and
// each wave ds_read_b128's its 12 B-frags. Stage loads issued one step
// early (T14), X prefetched 2 steps ahead (named regs, unroll-2).
// Numerics identical to passing rounds: 3-term split, PROD6 order, fp32
// MFMA accum; only partial-sum grouping differs (2-way vs 4-way, ~1e-6).

constexpr int E_EXPERTS = 64;
constexpr int H_DIM = 4096;
constexpr int BLOCK = 512;   // 8 waves
constexpr int ROWS_B = 64;   // rows per block
constexpr int NSTEP = 64;    // 32-k steps per K-half
constexpr int KHALF = 2048;
constexpr int SROW = 40;     // shorts per expert row in stage (32 + 8 pad)
                             // 80 B stride: 16B-aligned b128, 2-way banks
constexpr int PSTR = E_EXPERTS * SROW;  // plane stride (shorts) = 2560
constexpr int QSTR = 3 * PSTR;          // K-half stride = 7680
constexpr int BSTR = 2 * QSTR;          // buffer stride = 15360 (30720 B)
constexpr int W_ELEMS = E_EXPERTS * H_DIM;

typedef __attribute__((ext_vector_type(8))) short short8;
typedef __attribute__((ext_vector_type(4))) float f32x4;

__device__ __forceinline__ float4 ld4(const float* p) {
  return *reinterpret_cast<const float4*>(p);
}
__device__ __forceinline__ short8 lds8(const unsigned short* p) {
  return *reinterpret_cast<const short8*>(p);
}

__device__ __forceinline__ unsigned short bf_rne(float x) {
  unsigned u = __builtin_bit_cast(unsigned, x);
  return (unsigned short)((u + 0x7fffu + ((u >> 16) & 1u)) >> 16);
}
__device__ __forceinline__ float bf2f(unsigned short b) {
  return __builtin_bit_cast(float, ((unsigned)b) << 16);
}
// x = h + m + l + err, |err| <= 2^-25 |x|. (h,m trunc; l RNE; residuals exact)
__device__ __forceinline__ void split3(float x, unsigned short& h,
                                       unsigned short& m, unsigned short& l) {
  unsigned short hb = (unsigned short)(__builtin_bit_cast(unsigned, x) >> 16);
  float r1 = x - bf2f(hb);
  unsigned short mb = (unsigned short)(__builtin_bit_cast(unsigned, r1) >> 16);
  float r2 = r1 - bf2f(mb);
  h = hb;
  m = mb;
  l = bf_rne(r2);
}
__device__ __forceinline__ void split3_8(float4 a, float4 b, short8& h,
                                         short8& m, short8& l) {
  unsigned short hh, mm, ll;
  split3(a.x, hh, mm, ll); h[0] = (short)hh; m[0] = (short)mm; l[0] = (short)ll;
  split3(a.y, hh, mm, ll); h[1] = (short)hh; m[1] = (short)mm; l[1] = (short)ll;
  split3(a.z, hh, mm, ll); h[2] = (short)hh; m[2] = (short)mm; l[2] = (short)ll;
  split3(a.w, hh, mm, ll); h[3] = (short)hh; m[3] = (short)mm; l[3] = (short)ll;
  split3(b.x, hh, mm, ll); h[4] = (short)hh; m[4] = (short)mm; l[4] = (short)ll;
  split3(b.y, hh, mm, ll); h[5] = (short)hh; m[5] = (short)mm; l[5] = (short)ll;
  split3(b.z, hh, mm, ll); h[6] = (short)hh; m[6] = (short)mm; l[6] = (short)ll;
  split3(b.w, hh, mm, ll); h[7] = (short)hh; m[7] = (short)mm; l[7] = (short)ll;
}

// Pre-kernel: split W into h/m/l bf16 planes (same math as split3).
__global__ __launch_bounds__(256) void split_w_kernel(
    const float* __restrict__ w, unsigned short* __restrict__ wh,
    unsigned short* __restrict__ wm, unsigned short* __restrict__ wl) {
  const int i = (blockIdx.x * 256 + threadIdx.x) * 4;
  float4 v = ld4(w + i);
  ushort4 h4, m4, l4;
  split3(v.x, h4.x, m4.x, l4.x);
  split3(v.y, h4.y, m4.y, l4.y);
  split3(v.z, h4.z, m4.z, l4.z);
  split3(v.w, h4.w, m4.w, l4.w);
  *reinterpret_cast<ushort4*>(wh + i) = h4;
  *reinterpret_cast<ushort4*>(wm + i) = m4;
  *reinterpret_cast<ushort4*>(wl + i) = l4;
}

__global__ __launch_bounds__(BLOCK, 2) void topk_router_mfma(
    const float* __restrict__ x, const unsigned short* __restrict__ wh,
    const unsigned short* __restrict__ wm,
    const unsigned short* __restrict__ wl, const float* __restrict__ bias,
    float* __restrict__ out_final, float* __restrict__ out_idx) {
  __shared__ short smem[2 * BSTR];  // 61440 B; aliased as fp32 partials later

  const int tid = threadIdx.x;
  const int lane = tid & 63;
  const int wid = tid >> 6;
  const int rg = wid & 3;   // row group: rows rg*16..+15
  const int kq = wid >> 2;  // K half
  const int rowBase = blockIdx.x * ROWS_B;
  const int lr = lane & 15;
  const int kg = lane >> 4;

  // Staging assignment: thread t stages one short8 per plane per step.
  const int sw = tid & 255;
  const int se = sw >> 2;    // expert row 0..63
  const int sk8 = tid & 3;   // 8-k group within the 32-k tile
  const int skq = tid >> 8;  // which K-half tile
  const size_t gbase = (size_t)se * H_DIM + skq * KHALF + sk8 * 8;
  const int lbase = skq * QSTR + se * SROW + sk8 * 8;

  const float* __restrict__ xp =
      x + (size_t)(rowBase + rg * 16 + lr) * H_DIM + kq * KHALF + kg * 8;

  short8 s0, s1, s2;  // in-flight staged W (one short8 per plane)
  float4 xA0, xA1, xB0, xB1;

  f32x4 acc0 = {0.f, 0.f, 0.f, 0.f}, acc1 = acc0, acc2 = acc0, acc3 = acc0;

#define SLOAD(s)                        \
  do {                                  \
    const size_t go = gbase + (s) * 32; \
    s0 = lds8(wh + go);                 \
    s1 = lds8(wm + go);                 \
    s2 = lds8(wl + go);                 \
  } while (0)

#define SWRITE(buf)                                                         \
  do {                                                                      \
    *reinterpret_cast<short8*>(&smem[(buf)*BSTR + lbase + 0 * PSTR]) = s0;  \
    *reinterpret_cast<short8*>(&smem[(buf)*BSTR + lbase + 1 * PSTR]) = s1;  \
    *reinterpret_cast<short8*>(&smem[(buf)*BSTR + lbase + 2 * PSTR]) = s2;  \
  } while (0)

#define XLOAD(d0, d1, s)                  \
  do {                                    \
    d0 = ld4(xp + (size_t)(s) * 32);      \
    d1 = ld4(xp + (size_t)(s) * 32 + 4);  \
  } while (0)

  // Prologue: buf0 <- step 0; regs <- step 1; X <- steps 0,1.
  SLOAD(0);
  SWRITE(0);
  SLOAD(1);
  XLOAD(xA0, xA1, 0);
  XLOAD(xB0, xB1, 1);
  __syncthreads();

  const int fbase = kq * QSTR + lr * SROW + kg * 8;

#define FRAGS(buf, g, p)                      \
  (*reinterpret_cast<const short8*>(          \
      &smem[(buf)*BSTR + fbase + (g)*16 * SROW + (p)*PSTR]))

#define MM(d, a, b) d = __builtin_amdgcn_mfma_f32_16x16x32_bf16(a, b, d, 0, 0, 0)
#define PROD6(d, Ah, Am, Al, Bh, Bm, Bl)                      \
  MM(d, Ah, Bh); MM(d, Ah, Bm); MM(d, Am, Bh); MM(d, Am, Bm); \
  MM(d, Ah, Bl); MM(d, Al, Bh)

#define PHASE(s, buf, XF0, XF1)                                     \
  do {                                                              \
    if ((s) + 1 < NSTEP) SWRITE(1 - (buf)); /* tile for step s+1 */ \
    if ((s) + 2 < NSTEP) SLOAD((s) + 2);    /* early-issue (T14) */ \
    short8 b0h = FRAGS(buf, 0, 0), b0m = FRAGS(buf, 0, 1),          \
           b0l = FRAGS(buf, 0, 2);                                  \
    short8 b1h = FRAGS(buf, 1, 0), b1m = FRAGS(buf, 1, 1),          \
           b1l = FRAGS(buf, 1, 2);                                  \
    short8 b2h = FRAGS(buf, 2, 0), b2m = FRAGS(buf, 2, 1),          \
           b2l = FRAGS(buf, 2, 2);                                  \
    short8 b3h = FRAGS(buf, 3, 0), b3m = FRAGS(buf, 3, 1),          \
           b3l = FRAGS(buf, 3, 2);                                  \
    short8 ah, am, al;                                              \
    split3_8(XF0, XF1, ah, am, al);                                 \
    if ((s) + 2 < NSTEP) XLOAD(XF0, XF1, (s) + 2);                  \
    PROD6(acc0, ah, am, al, b0h, b0m, b0l);                         \
    PROD6(acc1, ah, am, al, b1h, b1m, b1l);                         \
    PROD6(acc2, ah, am, al, b2h, b2m, b2l);                         \
    PROD6(acc3, ah, am, al, b3h, b3m, b3l);                         \
    __syncthreads();                                                \
  } while (0)

  for (int s = 0; s < NSTEP; s += 2) {
    PHASE(s, 0, xA0, xA1);
    PHASE(s + 1, 1, xB0, xB1);
  }

  // Partials into LDS (aliased over the stage buffers; loop ended with a
  // barrier so all stage reads are done). Layout: part[(kq*64 + row)*68 + e].
  float* part = reinterpret_cast<float*>(smem);
  const int pr = kg * 4;
#define PSTORE(A, g)                                                       \
  part[((size_t)kq * 64 + rg * 16 + pr + 0) * 68 + (g)*16 + lr] = A[0];    \
  part[((size_t)kq * 64 + rg * 16 + pr + 1) * 68 + (g)*16 + lr] = A[1];    \
  part[((size_t)kq * 64 + rg * 16 + pr + 2) * 68 + (g)*16 + lr] = A[2];    \
  part[((size_t)kq * 64 + rg * 16 + pr + 3) * 68 + (g)*16 + lr] = A[3];
  PSTORE(acc0, 0)
  PSTORE(acc1, 1)
  PSTORE(acc2, 2)
  PSTORE(acc3, 3)
  __syncthreads();

  // Epilogue: 8 threads/row, 8 experts each; ordered 2-way partial sum,
  // stable top-2 scan, shfl_xor merge (d=1,2,4), softmax, scatter.
  const int r = tid >> 3;
  const int eb = (tid & 7) * 8;
  const int n = rowBase + r;

  float v8[8];
#pragma unroll
  for (int j = 0; j < 8; ++j) {
    int e = eb + j;
    v8[j] = (part[(size_t)r * 68 + e] + part[(size_t)(64 + r) * 68 + e]) +
            bias[e];
  }

  float av = -INFINITY, bv = -INFINITY;
  int ai = E_EXPERTS, bi = E_EXPERTS;
#pragma unroll
  for (int j = 0; j < 8; ++j) {
    int e = eb + j;
    float v = v8[j];
    bool beats_a = (v > av) || (v == av && e < ai);
    bool beats_b = (v > bv) || (v == bv && e < bi);
    if (beats_a) {
      bv = av; bi = ai; av = v; ai = e;
    } else if (beats_b) {
      bv = v; bi = e;
    }
  }
#pragma unroll
  for (int d = 1; d < 8; d <<= 1) {
    float av2 = __shfl_xor(av, d);
    float bv2 = __shfl_xor(bv, d);
    int ai2 = __shfl_xor(ai, d);
    int bi2 = __shfl_xor(bi, d);
    bool afirst = (av > av2) || (av == av2 && ai < ai2);
    float na, nb;
    int nai, nbi;
    if (afirst) {
      na = av; nai = ai;
      bool t = (bv > av2) || (bv == av2 && bi < ai2);
      nb = t ? bv : av2;
      nbi = t ? bi : ai2;
    } else {
      na = av2; nai = ai2;
      bool t = (av > bv2) || (av == bv2 && ai < bi2);
      nb = t ? av : bv2;
      nbi = t ? ai : bi2;
    }
    av = na; ai = nai; bv = nb; bi = nbi;
  }

  float e1 = expf(bv - av);
  float denom = 1.0f + e1;
  float p0 = 1.0f / denom;
  float p1 = e1 / denom;

#pragma unroll
  for (int i = 0; i < 2; ++i) {
    float4 o4;
    float* po = &o4.x;
#pragma unroll
    for (int j = 0; j < 4; ++j) {
      int e = eb + i * 4 + j;
      po[j] = (e == ai) ? p0 : (e == bi) ? p1 : 0.0f;
    }
    *reinterpret_cast<float4*>(&out_final[(size_t)n * E_EXPERTS + eb + i * 4]) =
        o4;
  }
  if ((tid & 7) == 0) {
    out_idx[(size_t)n * 2 + 0] = (float)ai;
    out_idx[(size_t)n * 2 + 1] = (float)bi;
  }
}

extern "C" void kernel_launch(void* const* d_in, const int* in_sizes, int n_in,
                              void* d_out, int out_size, void* d_ws,
                              size_t ws_size, hipStream_t stream) {
  const float* x = (const float*)d_in[0];
  const float* w = (const float*)d_in[1];
  const float* bias = (const float*)d_in[2];
  const int N = in_sizes[0] / H_DIM;  // 16384
  float* out_final = (float*)d_out;
  float* out_idx = out_final + (size_t)N * E_EXPERTS;

  unsigned short* wh = (unsigned short*)d_ws;  // 3 planes x 512 KB
  unsigned short* wm = wh + W_ELEMS;
  unsigned short* wl = wm + W_ELEMS;

  split_w_kernel<<<W_ELEMS / (256 * 4), 256, 0, stream>>>(w, wh, wm, wl);
  topk_router_mfma<<<N / ROWS_B, BLOCK, 0, stream>>>(x, wh, wm, wl, bias,
                                                     out_final, out_idx);
}

// Round 9
// 101.183 us; speedup vs baseline: 1.3479x; 1.0136x over previous
//
#include <hip/hip_runtime.h>
#include <math.h>

// TopK router: logits = x @ W^T + bias; top-2; softmax over the 2; scatter.
// x: [N=16384, H=4096] fp32, W: [E=64, H=4096] fp32, bias: [64] fp32.
// d_out: [N*64] final (fp32) then [N*2] selected_experts written as floats.
//
// Round 9 = round 8 (W pre-split h/m/l bf16 planes; double-buffered LDS
// staging; 3-term split; PROD6; X reg-prefetch 2 steps) with ONE change:
// __syncthreads() -> [s_waitcnt lgkmcnt(0); raw s_barrier]. __syncthreads
// emits a full vmcnt(0) drain before s_barrier (m97 stall), which killed
// the W-stage and X prefetch every step (phase = work + exposed L2/HBM
// latency -> 102 us vs ~50 us model). Raw barrier + lgkmcnt(0) keeps LDS
// producer/consumer ordering (dbuf, 1 barrier/phase) while vmcnt stays
// counted -- stage loads span barriers (T4). No in-loop cross-wave data
// flows through global memory, so skipping the vmcnt drain is safe.

constexpr int E_EXPERTS = 64;
constexpr int H_DIM = 4096;
constexpr int BLOCK = 512;   // 8 waves
constexpr int ROWS_B = 64;   // rows per block
constexpr int NSTEP = 64;    // 32-k steps per K-half
constexpr int KHALF = 2048;
constexpr int SROW = 40;     // shorts per expert row in stage (32 + 8 pad)
constexpr int PSTR = E_EXPERTS * SROW;  // plane stride (shorts) = 2560
constexpr int QSTR = 3 * PSTR;          // K-half stride = 7680
constexpr int BSTR = 2 * QSTR;          // buffer stride = 15360
constexpr int W_ELEMS = E_EXPERTS * H_DIM;

typedef __attribute__((ext_vector_type(8))) short short8;
typedef __attribute__((ext_vector_type(4))) float f32x4;

__device__ __forceinline__ float4 ld4(const float* p) {
  return *reinterpret_cast<const float4*>(p);
}
__device__ __forceinline__ short8 lds8(const unsigned short* p) {
  return *reinterpret_cast<const short8*>(p);
}

// Producer-correct light barrier: own LDS ops complete, vmcnt NOT drained.
__device__ __forceinline__ void block_barrier() {
  asm volatile("s_waitcnt lgkmcnt(0)" ::: "memory");
  __builtin_amdgcn_s_barrier();
}

__device__ __forceinline__ unsigned short bf_rne(float x) {
  unsigned u = __builtin_bit_cast(unsigned, x);
  return (unsigned short)((u + 0x7fffu + ((u >> 16) & 1u)) >> 16);
}
__device__ __forceinline__ float bf2f(unsigned short b) {
  return __builtin_bit_cast(float, ((unsigned)b) << 16);
}
// x = h + m + l + err, |err| <= 2^-25 |x|. (h,m trunc; l RNE; residuals exact)
__device__ __forceinline__ void split3(float x, unsigned short& h,
                                       unsigned short& m, unsigned short& l) {
  unsigned short hb = (unsigned short)(__builtin_bit_cast(unsigned, x) >> 16);
  float r1 = x - bf2f(hb);
  unsigned short mb = (unsigned short)(__builtin_bit_cast(unsigned, r1) >> 16);
  float r2 = r1 - bf2f(mb);
  h = hb;
  m = mb;
  l = bf_rne(r2);
}
__device__ __forceinline__ void split3_8(float4 a, float4 b, short8& h,
                                         short8& m, short8& l) {
  unsigned short hh, mm, ll;
  split3(a.x, hh, mm, ll); h[0] = (short)hh; m[0] = (short)mm; l[0] = (short)ll;
  split3(a.y, hh, mm, ll); h[1] = (short)hh; m[1] = (short)mm; l[1] = (short)ll;
  split3(a.z, hh, mm, ll); h[2] = (short)hh; m[2] = (short)mm; l[2] = (short)ll;
  split3(a.w, hh, mm, ll); h[3] = (short)hh; m[3] = (short)mm; l[3] = (short)ll;
  split3(b.x, hh, mm, ll); h[4] = (short)hh; m[4] = (short)mm; l[4] = (short)ll;
  split3(b.y, hh, mm, ll); h[5] = (short)hh; m[5] = (short)mm; l[5] = (short)ll;
  split3(b.z, hh, mm, ll); h[6] = (short)hh; m[6] = (short)mm; l[6] = (short)ll;
  split3(b.w, hh, mm, ll); h[7] = (short)hh; m[7] = (short)mm; l[7] = (short)ll;
}

// Pre-kernel: split W into h/m/l bf16 planes (same math as split3).
__global__ __launch_bounds__(256) void split_w_kernel(
    const float* __restrict__ w, unsigned short* __restrict__ wh,
    unsigned short* __restrict__ wm, unsigned short* __restrict__ wl) {
  const int i = (blockIdx.x * 256 + threadIdx.x) * 4;
  float4 v = ld4(w + i);
  ushort4 h4, m4, l4;
  split3(v.x, h4.x, m4.x, l4.x);
  split3(v.y, h4.y, m4.y, l4.y);
  split3(v.z, h4.z, m4.z, l4.z);
  split3(v.w, h4.w, m4.w, l4.w);
  *reinterpret_cast<ushort4*>(wh + i) = h4;
  *reinterpret_cast<ushort4*>(wm + i) = m4;
  *reinterpret_cast<ushort4*>(wl + i) = l4;
}

__global__ __launch_bounds__(BLOCK, 2) void topk_router_mfma(
    const float* __restrict__ x, const unsigned short* __restrict__ wh,
    const unsigned short* __restrict__ wm,
    const unsigned short* __restrict__ wl, const float* __restrict__ bias,
    float* __restrict__ out_final, float* __restrict__ out_idx) {
  __shared__ short smem[2 * BSTR];  // 61440 B; aliased as fp32 partials later

  const int tid = threadIdx.x;
  const int lane = tid & 63;
  const int wid = tid >> 6;
  const int rg = wid & 3;   // row group: rows rg*16..+15
  const int kq = wid >> 2;  // K half
  const int rowBase = blockIdx.x * ROWS_B;
  const int lr = lane & 15;
  const int kg = lane >> 4;

  // Staging assignment: thread t stages one short8 per plane per step.
  const int sw = tid & 255;
  const int se = sw >> 2;    // expert row 0..63
  const int sk8 = tid & 3;   // 8-k group within the 32-k tile
  const int skq = tid >> 8;  // which K-half tile
  const size_t gbase = (size_t)se * H_DIM + skq * KHALF + sk8 * 8;
  const int lbase = skq * QSTR + se * SROW + sk8 * 8;

  const float* __restrict__ xp =
      x + (size_t)(rowBase + rg * 16 + lr) * H_DIM + kq * KHALF + kg * 8;

  short8 s0, s1, s2;  // in-flight staged W (one short8 per plane)
  float4 xA0, xA1, xB0, xB1;

  f32x4 acc0 = {0.f, 0.f, 0.f, 0.f}, acc1 = acc0, acc2 = acc0, acc3 = acc0;

#define SLOAD(s)                        \
  do {                                  \
    const size_t go = gbase + (s) * 32; \
    s0 = lds8(wh + go);                 \
    s1 = lds8(wm + go);                 \
    s2 = lds8(wl + go);                 \
  } while (0)

#define SWRITE(buf)                                                         \
  do {                                                                      \
    *reinterpret_cast<short8*>(&smem[(buf)*BSTR + lbase + 0 * PSTR]) = s0;  \
    *reinterpret_cast<short8*>(&smem[(buf)*BSTR + lbase + 1 * PSTR]) = s1;  \
    *reinterpret_cast<short8*>(&smem[(buf)*BSTR + lbase + 2 * PSTR]) = s2;  \
  } while (0)

#define XLOAD(d0, d1, s)                  \
  do {                                    \
    d0 = ld4(xp + (size_t)(s) * 32);      \
    d1 = ld4(xp + (size_t)(s) * 32 + 4);  \
  } while (0)

  // Prologue: buf0 <- step 0; regs <- step 1; X <- steps 0,1.
  SLOAD(0);
  SWRITE(0);
  SLOAD(1);
  XLOAD(xA0, xA1, 0);
  XLOAD(xB0, xB1, 1);
  block_barrier();

  const int fbase = kq * QSTR + lr * SROW + kg * 8;

#define FRAGS(buf, g, p)                      \
  (*reinterpret_cast<const short8*>(          \
      &smem[(buf)*BSTR + fbase + (g)*16 * SROW + (p)*PSTR]))

#define MM(d, a, b) d = __builtin_amdgcn_mfma_f32_16x16x32_bf16(a, b, d, 0, 0, 0)
#define PROD6(d, Ah, Am, Al, Bh, Bm, Bl)                      \
  MM(d, Ah, Bh); MM(d, Ah, Bm); MM(d, Am, Bh); MM(d, Am, Bm); \
  MM(d, Ah, Bl); MM(d, Al, Bh)

#define PHASE(s, buf, XF0, XF1)                                     \
  do {                                                              \
    if ((s) + 1 < NSTEP) SWRITE(1 - (buf)); /* tile for step s+1 */ \
    if ((s) + 2 < NSTEP) SLOAD((s) + 2);    /* stays in flight */   \
    short8 b0h = FRAGS(buf, 0, 0), b0m = FRAGS(buf, 0, 1),          \
           b0l = FRAGS(buf, 0, 2);                                  \
    short8 b1h = FRAGS(buf, 1, 0), b1m = FRAGS(buf, 1, 1),          \
           b1l = FRAGS(buf, 1, 2);                                  \
    short8 b2h = FRAGS(buf, 2, 0), b2m = FRAGS(buf, 2, 1),          \
           b2l = FRAGS(buf, 2, 2);                                  \
    short8 b3h = FRAGS(buf, 3, 0), b3m = FRAGS(buf, 3, 1),          \
           b3l = FRAGS(buf, 3, 2);                                  \
    short8 ah, am, al;                                              \
    split3_8(XF0, XF1, ah, am, al);                                 \
    if ((s) + 2 < NSTEP) XLOAD(XF0, XF1, (s) + 2);                  \
    PROD6(acc0, ah, am, al, b0h, b0m, b0l);                         \
    PROD6(acc1, ah, am, al, b1h, b1m, b1l);                         \
    PROD6(acc2, ah, am, al, b2h, b2m, b2l);                         \
    PROD6(acc3, ah, am, al, b3h, b3m, b3l);                         \
    block_barrier();                                                \
  } while (0)

  for (int s = 0; s < NSTEP; s += 2) {
    PHASE(s, 0, xA0, xA1);
    PHASE(s + 1, 1, xB0, xB1);
  }

  // Partials into LDS (aliased over the stage buffers; loop ended with a
  // barrier so all stage reads are done). Layout: part[(kq*64 + row)*68 + e].
  float* part = reinterpret_cast<float*>(smem);
  const int pr = kg * 4;
#define PSTORE(A, g)                                                       \
  part[((size_t)kq * 64 + rg * 16 + pr + 0) * 68 + (g)*16 + lr] = A[0];    \
  part[((size_t)kq * 64 + rg * 16 + pr + 1) * 68 + (g)*16 + lr] = A[1];    \
  part[((size_t)kq * 64 + rg * 16 + pr + 2) * 68 + (g)*16 + lr] = A[2];    \
  part[((size_t)kq * 64 + rg * 16 + pr + 3) * 68 + (g)*16 + lr] = A[3];
  PSTORE(acc0, 0)
  PSTORE(acc1, 1)
  PSTORE(acc2, 2)
  PSTORE(acc3, 3)
  block_barrier();

  // Epilogue: 8 threads/row, 8 experts each; ordered 2-way partial sum,
  // stable top-2 scan, shfl_xor merge (d=1,2,4), softmax, scatter.
  const int r = tid >> 3;
  const int eb = (tid & 7) * 8;
  const int n = rowBase + r;

  float v8[8];
#pragma unroll
  for (int j = 0; j < 8; ++j) {
    int e = eb + j;
    v8[j] = (part[(size_t)r * 68 + e] + part[(size_t)(64 + r) * 68 + e]) +
            bias[e];
  }

  float av = -INFINITY, bv = -INFINITY;
  int ai = E_EXPERTS, bi = E_EXPERTS;
#pragma unroll
  for (int j = 0; j < 8; ++j) {
    int e = eb + j;
    float v = v8[j];
    bool beats_a = (v > av) || (v == av && e < ai);
    bool beats_b = (v > bv) || (v == bv && e < bi);
    if (beats_a) {
      bv = av; bi = ai; av = v; ai = e;
    } else if (beats_b) {
      bv = v; bi = e;
    }
  }
#pragma unroll
  for (int d = 1; d < 8; d <<= 1) {
    float av2 = __shfl_xor(av, d);
    float bv2 = __shfl_xor(bv, d);
    int ai2 = __shfl_xor(ai, d);
    int bi2 = __shfl_xor(bi, d);
    bool afirst = (av > av2) || (av == av2 && ai < ai2);
    float na, nb;
    int nai, nbi;
    if (afirst) {
      na = av; nai = ai;
      bool t = (bv > av2) || (bv == av2 && bi < ai2);
      nb = t ? bv : av2;
      nbi = t ? bi : ai2;
    } else {
      na = av2; nai = ai2;
      bool t = (av > bv2) || (av == bv2 && ai < bi2);
      nb = t ? av : bv2;
      nbi = t ? ai : bi2;
    }
    av = na; ai = nai; bv = nb; bi = nbi;
  }

  float e1 = expf(bv - av);
  float denom = 1.0f + e1;
  float p0 = 1.0f / denom;
  float p1 = e1 / denom;

#pragma unroll
  for (int i = 0; i < 2; ++i) {
    float4 o4;
    float* po = &o4.x;
#pragma unroll
    for (int j = 0; j < 4; ++j) {
      int e = eb + i * 4 + j;
      po[j] = (e == ai) ? p0 : (e == bi) ? p1 : 0.0f;
    }
    *reinterpret_cast<float4*>(&out_final[(size_t)n * E_EXPERTS + eb + i * 4]) =
        o4;
  }
  if ((tid & 7) == 0) {
    out_idx[(size_t)n * 2 + 0] = (float)ai;
    out_idx[(size_t)n * 2 + 1] = (float)bi;
  }
}

extern "C" void kernel_launch(void* const* d_in, const int* in_sizes, int n_in,
                              void* d_out, int out_size, void* d_ws,
                              size_t ws_size, hipStream_t stream) {
  const float* x = (const float*)d_in[0];
  const float* w = (const float*)d_in[1];
  const float* bias = (const float*)d_in[2];
  const int N = in_sizes[0] / H_DIM;  // 16384
  float* out_final = (float*)d_out;
  float* out_idx = out_final + (size_t)N * E_EXPERTS;

  unsigned short* wh = (unsigned short*)d_ws;  // 3 planes x 512 KB
  unsigned short* wm = wh + W_ELEMS;
  unsigned short* wl = wm + W_ELEMS;

  split_w_kernel<<<W_ELEMS / (256 * 4), 256, 0, stream>>>(w, wh, wm, wl);
  topk_router_mfma<<<N / ROWS_B, BLOCK, 0, stream>>>(x, wh, wm, wl, bias,
                                                     out_final, out_idx);
}

// Round 10
// 91.704 us; speedup vs baseline: 1.4873x; 1.1034x over previous
//
#include <hip/hip_runtime.h>
#include <math.h>

// TopK router: logits = x @ W^T + bias; top-2; softmax over the 2; scatter.
// x: [N=16384, H=4096] fp32, W: [E=64, H=4096] fp32, bias: [64] fp32.
// d_out: [N*64] final (fp32) then [N*2] selected_experts written as floats.
//
// Round 10: rounds 8/9 measured 3790 cyc/step ~= the SERIAL SUM of pipe
// demands (LDS 1440 + HBM 1600 + VALU/MFMA ~700): lockstep waves burst on
// the same pipe between barriers, and 4 rg-mate waves read identical
// B-frags (4x LDS replication). Reshape: waves = 4 K-slices x 2 row-halves
// (32 rows, 2 A-frags each). B-frag replication 4x -> 2x; phases 64 -> 32,
// each 4x bigger and HBM-paced (X-stream 3200 cyc/phase dominates; LDS
// 1730, VALU 400, MFMA 480 fit underneath). W tile/phase = 48 KB dbuf'd
// (120 KB LDS); 1-phase lookahead for W stage + X regs. Numerics and
// layouts byte-identical to passing rounds; 4-way kq partial-sum tree
// (= round 5). Light barrier (lgkmcnt only) kept from round 9.

constexpr int E_EXPERTS = 64;
constexpr int H_DIM = 4096;
constexpr int BLOCK = 512;   // 8 waves = 4 kq-slices x 2 row-halves
constexpr int ROWS_B = 64;   // rows per block
constexpr int NPH = 32;      // phases; 32 k per slice per phase
constexpr int KSLICE = 1024; // k per kq slice
constexpr int SROW = 40;     // shorts per (kq,plane,e) row: 32 + 8 pad
constexpr int BUFS = 12 * 64 * SROW;  // 30720 shorts = 61440 B per buffer
constexpr int W_ELEMS = E_EXPERTS * H_DIM;

typedef __attribute__((ext_vector_type(8))) short short8;
typedef __attribute__((ext_vector_type(4))) float f32x4;

__device__ __forceinline__ float4 ld4(const float* p) {
  return *reinterpret_cast<const float4*>(p);
}
__device__ __forceinline__ short8 lds8(const unsigned short* p) {
  return *reinterpret_cast<const short8*>(p);
}

// Light barrier: own LDS ops complete, vmcnt NOT drained (round 9, proven).
__device__ __forceinline__ void block_barrier() {
  asm volatile("s_waitcnt lgkmcnt(0)" ::: "memory");
  __builtin_amdgcn_s_barrier();
}

__device__ __forceinline__ unsigned short bf_rne(float x) {
  unsigned u = __builtin_bit_cast(unsigned, x);
  return (unsigned short)((u + 0x7fffu + ((u >> 16) & 1u)) >> 16);
}
__device__ __forceinline__ float bf2f(unsigned short b) {
  return __builtin_bit_cast(float, ((unsigned)b) << 16);
}
// x = h + m + l + err, |err| <= 2^-25 |x|. (h,m trunc; l RNE; residuals exact)
__device__ __forceinline__ void split3(float x, unsigned short& h,
                                       unsigned short& m, unsigned short& l) {
  unsigned short hb = (unsigned short)(__builtin_bit_cast(unsigned, x) >> 16);
  float r1 = x - bf2f(hb);
  unsigned short mb = (unsigned short)(__builtin_bit_cast(unsigned, r1) >> 16);
  float r2 = r1 - bf2f(mb);
  h = hb;
  m = mb;
  l = bf_rne(r2);
}
__device__ __forceinline__ void split3_8(float4 a, float4 b, short8& h,
                                         short8& m, short8& l) {
  unsigned short hh, mm, ll;
  split3(a.x, hh, mm, ll); h[0] = (short)hh; m[0] = (short)mm; l[0] = (short)ll;
  split3(a.y, hh, mm, ll); h[1] = (short)hh; m[1] = (short)mm; l[1] = (short)ll;
  split3(a.z, hh, mm, ll); h[2] = (short)hh; m[2] = (short)mm; l[2] = (short)ll;
  split3(a.w, hh, mm, ll); h[3] = (short)hh; m[3] = (short)mm; l[3] = (short)ll;
  split3(b.x, hh, mm, ll); h[4] = (short)hh; m[4] = (short)mm; l[4] = (short)ll;
  split3(b.y, hh, mm, ll); h[5] = (short)hh; m[5] = (short)mm; l[5] = (short)ll;
  split3(b.z, hh, mm, ll); h[6] = (short)hh; m[6] = (short)mm; l[6] = (short)ll;
  split3(b.w, hh, mm, ll); h[7] = (short)hh; m[7] = (short)mm; l[7] = (short)ll;
}

// Pre-kernel: split W into h/m/l bf16 planes (same math as split3).
__global__ __launch_bounds__(256) void split_w_kernel(
    const float* __restrict__ w, unsigned short* __restrict__ wh,
    unsigned short* __restrict__ wm, unsigned short* __restrict__ wl) {
  const int i = (blockIdx.x * 256 + threadIdx.x) * 4;
  float4 v = ld4(w + i);
  ushort4 h4, m4, l4;
  split3(v.x, h4.x, m4.x, l4.x);
  split3(v.y, h4.y, m4.y, l4.y);
  split3(v.z, h4.z, m4.z, l4.z);
  split3(v.w, h4.w, m4.w, l4.w);
  *reinterpret_cast<ushort4*>(wh + i) = h4;
  *reinterpret_cast<ushort4*>(wm + i) = m4;
  *reinterpret_cast<ushort4*>(wl + i) = l4;
}

__global__ __launch_bounds__(BLOCK, 2) void topk_router_mfma(
    const float* __restrict__ x, const unsigned short* __restrict__ wh,
    const unsigned short* __restrict__ wm,
    const unsigned short* __restrict__ wl, const float* __restrict__ bias,
    float* __restrict__ out_final, float* __restrict__ out_idx) {
  __shared__ short smem[2 * BUFS];  // 122880 B; aliased as fp32 partials

  const int tid = threadIdx.x;
  const int lane = tid & 63;
  const int wid = tid >> 6;
  const int kq = wid & 3;   // K slice (1024 k)
  const int rh = wid >> 2;  // row half (32 rows)
  const int rowBase = blockIdx.x * ROWS_B;
  const int lr = lane & 15;
  const int kg = lane >> 4;

  // Staging: 48 KB/phase = 3072 x 16B units; 6 units per thread.
  // unit u = tid + 512*i: k8 = u&3, e = (u>>2)&63, pq = u>>8 = kq_s*3+plane
  // (pq is wave-uniform: 2i for waves 0-3, 2i+1 for waves 4-7).
#define DECL_UNIT(i)                                                       \
  const int u##i = tid + 512 * (i);                                        \
  const int pq##i = u##i >> 8;                                             \
  const int kqs##i = pq##i / 3;                                            \
  const int pl##i = pq##i - kqs##i * 3;                                    \
  const unsigned short* gp##i =                                            \
      (pl##i == 0 ? wh : (pl##i == 1 ? wm : wl)) +                         \
      (size_t)((u##i >> 2) & 63) * H_DIM + kqs##i * KSLICE + (u##i & 3) * 8; \
  const int lo##i = (pq##i * 64 + ((u##i >> 2) & 63)) * SROW + (u##i & 3) * 8; \
  short8 sv##i;
  DECL_UNIT(0) DECL_UNIT(1) DECL_UNIT(2)
  DECL_UNIT(3) DECL_UNIT(4) DECL_UNIT(5)

#define SLOAD(t)                                  \
  do {                                            \
    sv0 = lds8(gp0 + (size_t)(t) * 32);           \
    sv1 = lds8(gp1 + (size_t)(t) * 32);           \
    sv2 = lds8(gp2 + (size_t)(t) * 32);           \
    sv3 = lds8(gp3 + (size_t)(t) * 32);           \
    sv4 = lds8(gp4 + (size_t)(t) * 32);           \
    sv5 = lds8(gp5 + (size_t)(t) * 32);           \
  } while (0)

#define SWRITE(buf)                                                    \
  do {                                                                 \
    *reinterpret_cast<short8*>(&smem[(buf)*BUFS + lo0]) = sv0;         \
    *reinterpret_cast<short8*>(&smem[(buf)*BUFS + lo1]) = sv1;         \
    *reinterpret_cast<short8*>(&smem[(buf)*BUFS + lo2]) = sv2;         \
    *reinterpret_cast<short8*>(&smem[(buf)*BUFS + lo3]) = sv3;         \
    *reinterpret_cast<short8*>(&smem[(buf)*BUFS + lo4]) = sv4;         \
    *reinterpret_cast<short8*>(&smem[(buf)*BUFS + lo5]) = sv5;         \
  } while (0)

  // X: this wave's 32 rows (2 A-frags) x its 1024-k slice.
  const float* __restrict__ xr0 =
      x + (size_t)(rowBase + rh * 32 + lr) * H_DIM + kq * KSLICE + kg * 8;
  const float* __restrict__ xr1 = xr0 + (size_t)16 * H_DIM;

  float4 xA0, xA1, xA2, xA3, xB0, xB1, xB2, xB3;
#define XLOADA(t)                                \
  do {                                           \
    xA0 = ld4(xr0 + (size_t)(t) * 32);           \
    xA1 = ld4(xr0 + (size_t)(t) * 32 + 4);       \
    xA2 = ld4(xr1 + (size_t)(t) * 32);           \
    xA3 = ld4(xr1 + (size_t)(t) * 32 + 4);       \
  } while (0)
#define XLOADB(t)                                \
  do {                                           \
    xB0 = ld4(xr0 + (size_t)(t) * 32);           \
    xB1 = ld4(xr0 + (size_t)(t) * 32 + 4);       \
    xB2 = ld4(xr1 + (size_t)(t) * 32);           \
    xB3 = ld4(xr1 + (size_t)(t) * 32 + 4);       \
  } while (0)

  f32x4 accA0 = {0.f, 0.f, 0.f, 0.f}, accA1 = accA0, accA2 = accA0,
        accA3 = accA0, accB0 = accA0, accB1 = accA0, accB2 = accA0,
        accB3 = accA0;

  // Prologue: tile0 -> buf0; tile1 -> regs; X phases 0,1 -> regs.
  SLOAD(0);
  SWRITE(0);
  SLOAD(1);
  XLOADA(0);
  XLOADB(1);
  block_barrier();

#define FRAG(buf, eg, pl)                                              \
  (*reinterpret_cast<const short8*>(                                   \
      &smem[(buf)*BUFS + ((kq * 3 + (pl)) * 64 + (eg)*16 + lr) * SROW + \
            kg * 8]))

#define MM(d, a, b) d = __builtin_amdgcn_mfma_f32_16x16x32_bf16(a, b, d, 0, 0, 0)
#define PROD6(d, Ah, Am, Al, Bh, Bm, Bl)                      \
  MM(d, Ah, Bh); MM(d, Ah, Bm); MM(d, Am, Bh); MM(d, Am, Bm); \
  MM(d, Ah, Bl); MM(d, Al, Bh)

#define PHASE(p, buf, X0, X1, X2, X3, XLOADM)                        \
  do {                                                               \
    if ((p) + 1 < NPH) SWRITE((buf) ^ 1); /* tile p+1 from regs */   \
    if ((p) + 2 < NPH) SLOAD((p) + 2);    /* 1-phase lookahead */    \
    short8 b0h = FRAG(buf, 0, 0), b0m = FRAG(buf, 0, 1),             \
           b0l = FRAG(buf, 0, 2);                                    \
    short8 b1h = FRAG(buf, 1, 0), b1m = FRAG(buf, 1, 1),             \
           b1l = FRAG(buf, 1, 2);                                    \
    short8 b2h = FRAG(buf, 2, 0), b2m = FRAG(buf, 2, 1),             \
           b2l = FRAG(buf, 2, 2);                                    \
    short8 b3h = FRAG(buf, 3, 0), b3m = FRAG(buf, 3, 1),             \
           b3l = FRAG(buf, 3, 2);                                    \
    short8 ah0, am0, al0, ah1, am1, al1;                             \
    split3_8(X0, X1, ah0, am0, al0);                                 \
    split3_8(X2, X3, ah1, am1, al1);                                 \
    if ((p) + 2 < NPH) XLOADM((p) + 2); /* X 1-phase lookahead */    \
    PROD6(accA0, ah0, am0, al0, b0h, b0m, b0l);                      \
    PROD6(accA1, ah0, am0, al0, b1h, b1m, b1l);                      \
    PROD6(accA2, ah0, am0, al0, b2h, b2m, b2l);                      \
    PROD6(accA3, ah0, am0, al0, b3h, b3m, b3l);                      \
    PROD6(accB0, ah1, am1, al1, b0h, b0m, b0l);                      \
    PROD6(accB1, ah1, am1, al1, b1h, b1m, b1l);                      \
    PROD6(accB2, ah1, am1, al1, b2h, b2m, b2l);                      \
    PROD6(accB3, ah1, am1, al1, b3h, b3m, b3l);                      \
    block_barrier();                                                 \
  } while (0)

  for (int p = 0; p < NPH; p += 2) {
    PHASE(p, 0, xA0, xA1, xA2, xA3, XLOADA);
    PHASE(p + 1, 1, xB0, xB1, xB2, xB3, XLOADB);
  }

  // Partials: part[kq][row][e], row pad 68. 69632 B <= 122880 B (aliased;
  // loop ended with a barrier so all stage reads are done).
  float* part = reinterpret_cast<float*>(smem);
  const int pr = kg * 4;
  const int rwA = rh * 32 + pr;       // frag0 rows
  const int rwB = rh * 32 + 16 + pr;  // frag1 rows
#define PSTORE(A, rw, g)                                              \
  part[(size_t)(kq * 64 + (rw) + 0) * 68 + (g)*16 + lr] = A[0];       \
  part[(size_t)(kq * 64 + (rw) + 1) * 68 + (g)*16 + lr] = A[1];       \
  part[(size_t)(kq * 64 + (rw) + 2) * 68 + (g)*16 + lr] = A[2];       \
  part[(size_t)(kq * 64 + (rw) + 3) * 68 + (g)*16 + lr] = A[3];
  PSTORE(accA0, rwA, 0)
  PSTORE(accA1, rwA, 1)
  PSTORE(accA2, rwA, 2)
  PSTORE(accA3, rwA, 3)
  PSTORE(accB0, rwB, 0)
  PSTORE(accB1, rwB, 1)
  PSTORE(accB2, rwB, 2)
  PSTORE(accB3, rwB, 3)
  block_barrier();

  // Epilogue: 8 threads/row, 8 experts each; ordered 4-way partial sum
  // (= round 5), stable top-2 scan, shfl_xor merge, softmax, scatter.
  const int r = tid >> 3;
  const int eb = (tid & 7) * 8;
  const int n = rowBase + r;

  float v8[8];
#pragma unroll
  for (int j = 0; j < 8; ++j) {
    int e = eb + j;
    v8[j] = ((part[(size_t)(0 * 64 + r) * 68 + e] +
              part[(size_t)(1 * 64 + r) * 68 + e]) +
             (part[(size_t)(2 * 64 + r) * 68 + e] +
              part[(size_t)(3 * 64 + r) * 68 + e])) +
            bias[e];
  }

  float av = -INFINITY, bv = -INFINITY;
  int ai = E_EXPERTS, bi = E_EXPERTS;
#pragma unroll
  for (int j = 0; j < 8; ++j) {
    int e = eb + j;
    float v = v8[j];
    bool beats_a = (v > av) || (v == av && e < ai);
    bool beats_b = (v > bv) || (v == bv && e < bi);
    if (beats_a) {
      bv = av; bi = ai; av = v; ai = e;
    } else if (beats_b) {
      bv = v; bi = e;
    }
  }
#pragma unroll
  for (int d = 1; d < 8; d <<= 1) {
    float av2 = __shfl_xor(av, d);
    float bv2 = __shfl_xor(bv, d);
    int ai2 = __shfl_xor(ai, d);
    int bi2 = __shfl_xor(bi, d);
    bool afirst = (av > av2) || (av == av2 && ai < ai2);
    float na, nb;
    int nai, nbi;
    if (afirst) {
      na = av; nai = ai;
      bool t = (bv > av2) || (bv == av2 && bi < ai2);
      nb = t ? bv : av2;
      nbi = t ? bi : ai2;
    } else {
      na = av2; nai = ai2;
      bool t = (av > bv2) || (av == bv2 && ai < bi2);
      nb = t ? av : bv2;
      nbi = t ? ai : bi2;
    }
    av = na; ai = nai; bv = nb; bi = nbi;
  }

  float e1 = expf(bv - av);
  float denom = 1.0f + e1;
  float p0 = 1.0f / denom;
  float p1 = e1 / denom;

#pragma unroll
  for (int i = 0; i < 2; ++i) {
    float4 o4;
    float* po = &o4.x;
#pragma unroll
    for (int j = 0; j < 4; ++j) {
      int e = eb + i * 4 + j;
      po[j] = (e == ai) ? p0 : (e == bi) ? p1 : 0.0f;
    }
    *reinterpret_cast<float4*>(&out_final[(size_t)n * E_EXPERTS + eb + i * 4]) =
        o4;
  }
  if ((tid & 7) == 0) {
    out_idx[(size_t)n * 2 + 0] = (float)ai;
    out_idx[(size_t)n * 2 + 1] = (float)bi;
  }
}

extern "C" void kernel_launch(void* const* d_in, const int* in_sizes, int n_in,
                              void* d_out, int out_size, void* d_ws,
                              size_t ws_size, hipStream_t stream) {
  const float* x = (const float*)d_in[0];
  const float* w = (const float*)d_in[1];
  const float* bias = (const float*)d_in[2];
  const int N = in_sizes[0] / H_DIM;  // 16384
  float* out_final = (float*)d_out;
  float* out_idx = out_final + (size_t)N * E_EXPERTS;

  unsigned short* wh = (unsigned short*)d_ws;  // 3 planes x 512 KB
  unsigned short* wm = wh + W_ELEMS;
  unsigned short* wl = wm + W_ELEMS;

  split_w_kernel<<<W_ELEMS / (256 * 4), 256, 0, stream>>>(w, wh, wm, wl);
  topk_router_mfma<<<N / ROWS_B, BLOCK, 0, stream>>>(x, wh, wm, wl, bias,
                                                     out_final, out_idx);
}